// Round 11
// baseline (559.230 us; speedup 1.0000x reference)
//
#include <hip/hip_runtime.h>

#define NGRAPH 2048

typedef __attribute__((ext_vector_type(8))) short bf16x8;
typedef __attribute__((ext_vector_type(4))) float f32x4;
typedef __attribute__((ext_vector_type(8))) _Float16 h16x8;
typedef __attribute__((ext_vector_type(4))) _Float16 h16x4;

__device__ inline unsigned short bf16_rne(float f) {
  union { float f; unsigned u; } c; c.f = f;
  unsigned u = c.u + 0x7fffu + ((c.u >> 16) & 1u);
  return (unsigned short)(u >> 16);
}
__device__ inline float bf16_to_f32(unsigned short h) {
  union { float f; unsigned u; } c; c.u = ((unsigned)h) << 16;
  return c.f;
}

// ================= CSR build =================
__global__ __launch_bounds__(256) void scan1(
    const int* __restrict__ deg, int* __restrict__ rowstart, int* __restrict__ bsum, int N)
{
  __shared__ int tmp[256];
  int i = blockIdx.x * 256 + threadIdx.x;
  int v = (i < N) ? deg[i] : 0;
  tmp[threadIdx.x] = v;
  __syncthreads();
#pragma unroll
  for (int off = 1; off < 256; off <<= 1) {
    int t = (threadIdx.x >= (unsigned)off) ? tmp[threadIdx.x - off] : 0;
    __syncthreads();
    tmp[threadIdx.x] += t;
    __syncthreads();
  }
  if (i < N) rowstart[i] = tmp[threadIdx.x] - v;
  if (threadIdx.x == 255) bsum[blockIdx.x] = tmp[255];
}

__global__ __launch_bounds__(1024) void scan2(
    int* __restrict__ bsum, int nb, int* __restrict__ rowstart, int N, int E)
{
  __shared__ int tmp[1024];
  int i = threadIdx.x;
  int v = (i < nb) ? bsum[i] : 0;
  tmp[i] = v;
  __syncthreads();
#pragma unroll
  for (int off = 1; off < 1024; off <<= 1) {
    int t = (i >= off) ? tmp[i - off] : 0;
    __syncthreads();
    tmp[i] += t;
    __syncthreads();
  }
  if (i < nb) bsum[i] = tmp[i] - v;
  if (i == 0) rowstart[N] = E;
}

__global__ __launch_bounds__(256) void scan3(
    int* __restrict__ rowstart, const int* __restrict__ bsum, int N)
{
  int i = blockIdx.x * 256 + threadIdx.x;
  if (i < N) rowstart[i] += bsum[blockIdx.x];
}

__global__ __launch_bounds__(256) void fill_eidx(
    const int* __restrict__ src, const int* __restrict__ dst,
    const int* __restrict__ rowstart, int* __restrict__ cursor,
    int* __restrict__ eidx, int E)
{
  int e = blockIdx.x * 256 + threadIdx.x;
  if (e >= E) return;
  int d = dst[e];
  int pos = rowstart[d] + atomicAdd(&cursor[d], 1);
  eidx[pos] = src[e];
}

// ================= merged: degree histogram + 5x weight frag-repack + x pad =================
struct WPs {
  const float* w[5];
  unsigned short* hi[5];
  unsigned short* lo[5];
};
__global__ __launch_bounds__(256) void prep_hist(
    WPs p, const float* __restrict__ x, float* __restrict__ x8, int N,
    const int* __restrict__ dst, int* __restrict__ deg, int E)
{
  int g = blockIdx.x * 256 + threadIdx.x;
  if (g < E) {
    atomicAdd(&deg[dst[g]], 1);
    return;
  }
  int q = g - E;
  if (q < 5 * 16384) {
    int m = q >> 14;
    int j = q & 16383;
    int c = j >> 3, e = j & 7;
    int t = c >> 8, kc = (c >> 6) & 3, lane = c & 63;
    int n = t * 16 + (lane & 15);
    int k = kc * 32 + (lane >> 4) * 8 + e;
    float w = p.w[m][k * 128 + n];
    unsigned short h = bf16_rne(w);
    float r = w - bf16_to_f32(h);
    p.hi[m][j] = h;
    p.lo[m][j] = bf16_rne(r);
  } else {
    int i = q - 5 * 16384;
    if (i < N * 8) {
      int v = i >> 3, j = i & 7;
      x8[i] = (j < 7) ? x[v * 7 + j] : 0.f;
    }
  }
}

// ---- split-precision GEMM pass over a 64x128 fp16 LDS tile (chunk-rot swizzle) ----
__device__ inline void mfma_pass(
    const _Float16* __restrict__ zbuf,
    const unsigned short* __restrict__ Whi, const unsigned short* __restrict__ Wlo,
    int rw, int m16, int quad, int lane, f32x4 acc[8])
{
  int r = rw + m16;
  const _Float16* zrow = &zbuf[r * 128];
#pragma unroll
  for (int kc = 0; kc < 4; ++kc) {
    int cidx = kc * 4 + quad;
    h16x8 zh = *(const h16x8*)&zrow[((cidx + r) & 15) * 8];
    bf16x8 ah, al;
#pragma unroll
    for (int j = 0; j < 8; ++j) {
      float f = (float)zh[j];
      unsigned short h = bf16_rne(f);
      ah[j] = (short)h;
      al[j] = (short)bf16_rne(f - bf16_to_f32(h));
    }
#pragma unroll
    for (int t = 0; t < 8; ++t) {
      long cb = ((t * 4 + kc) * 64 + lane) * 8;
      bf16x8 bh = *(const bf16x8*)&Whi[cb];
      bf16x8 bl = *(const bf16x8*)&Wlo[cb];
      acc[t] = __builtin_amdgcn_mfma_f32_16x16x32_bf16(ah, bh, acc[t], 0, 0, 0);
      acc[t] = __builtin_amdgcn_mfma_f32_16x16x32_bf16(ah, bl, acc[t], 0, 0, 0);
      acc[t] = __builtin_amdgcn_mfma_f32_16x16x32_bf16(al, bh, acc[t], 0, 0, 0);
    }
  }
}

// ================= fused GIN layer (layers 2,3): gather + MLP1 + MLP2 =================
__global__ __launch_bounds__(256, 8) void fused_gin(
    const _Float16* __restrict__ H, const int* __restrict__ rowstart,
    const int* __restrict__ eidx,
    const unsigned short* __restrict__ W1hi, const unsigned short* __restrict__ W1lo,
    const float* __restrict__ B1,
    const unsigned short* __restrict__ W2hi, const unsigned short* __restrict__ W2lo,
    const float* __restrict__ B2,
    _Float16* __restrict__ Out, int M)
{
  __shared__ _Float16 zbuf[64 * 128];   // 16 KB
  int tid = threadIdx.x;
  int rbase = blockIdx.x * 64;

  // ---- phase 1: gather 64 rows; 16 lanes x 16B per row, 4-edge unroll ----
  {
    int sub = tid & 15;
    int ng = tid >> 4;
    const _Float16* Hc = H + sub * 8;
#pragma unroll
    for (int it = 0; it < 4; ++it) {
      int r = it * 16 + ng;
      int v = rbase + r;
      int vc = (v < M) ? v : (M - 1);
      h16x8 sv = *(const h16x8*)&Hc[(long)vc * 128];
      float a0[8], a1[8];
#pragma unroll
      for (int j = 0; j < 8; ++j) { a0[j] = (float)sv[j]; a1[j] = 0.f; }
      int e0 = rowstart[vc], e1 = rowstart[vc + 1];
      int e = e0;
      for (; e + 4 <= e1; e += 4) {
        int s0 = eidx[e], s1 = eidx[e + 1], s2 = eidx[e + 2], s3 = eidx[e + 3];
        h16x8 h0 = *(const h16x8*)&Hc[(long)s0 * 128];
        h16x8 h1 = *(const h16x8*)&Hc[(long)s1 * 128];
        h16x8 h2 = *(const h16x8*)&Hc[(long)s2 * 128];
        h16x8 h3 = *(const h16x8*)&Hc[(long)s3 * 128];
#pragma unroll
        for (int j = 0; j < 8; ++j) {
          a0[j] += (float)h0[j] + (float)h2[j];
          a1[j] += (float)h1[j] + (float)h3[j];
        }
      }
      for (; e < e1; ++e) {
        int s = eidx[e];
        h16x8 h = *(const h16x8*)&Hc[(long)s * 128];
#pragma unroll
        for (int j = 0; j < 8; ++j) a1[j] += (float)h[j];
      }
      h16x8 zo;
#pragma unroll
      for (int j = 0; j < 8; ++j) zo[j] = (_Float16)(a0[j] + a1[j]);
      *(h16x8*)&zbuf[r * 128 + ((sub + r) & 15) * 8] = zo;
    }
  }
  __syncthreads();

  int lane = tid & 63;
  int wv = tid >> 6;
  int m16 = lane & 15;
  int quad = lane >> 4;
  int rw = wv * 16;

  // ---- phase 2: y = relu(z @ W1 + b1) ----
  f32x4 acc[8];
#pragma unroll
  for (int t = 0; t < 8; ++t) acc[t] = (f32x4){0.f, 0.f, 0.f, 0.f};
  mfma_pass(zbuf, W1hi, W1lo, rw, m16, quad, lane, acc);

  float bias[8];
#pragma unroll
  for (int t = 0; t < 8; ++t) bias[t] = B1[t * 16 + m16];

  __syncthreads();
#pragma unroll
  for (int i = 0; i < 4; ++i) {
    int r = rw + quad * 4 + i;
#pragma unroll
    for (int t = 0; t < 8; ++t) {
      int col = t * 16 + m16;
      int cidx = col >> 3;
      zbuf[r * 128 + ((cidx + r) & 15) * 8 + (col & 7)] =
          (_Float16)fmaxf(acc[t][i] + bias[t], 0.f);
    }
  }
  __syncthreads();

  // ---- phase 3: Hout = relu(y @ W2 + b2), direct scattered fp16 stores ----
#pragma unroll
  for (int t = 0; t < 8; ++t) acc[t] = (f32x4){0.f, 0.f, 0.f, 0.f};
  mfma_pass(zbuf, W2hi, W2lo, rw, m16, quad, lane, acc);

#pragma unroll
  for (int t = 0; t < 8; ++t) bias[t] = B2[t * 16 + m16];

#pragma unroll
  for (int i = 0; i < 4; ++i) {
    int r = rbase + rw + quad * 4 + i;
    if (r < M) {
#pragma unroll
      for (int t = 0; t < 8; ++t) {
        float o = fmaxf(acc[t][i] + bias[t], 0.f);
        Out[(long)r * 128 + t * 16 + m16] = (_Float16)o;
      }
    }
  }
}

// ================= fused layer 1: gather(x8) + K=7 GEMM + MFMA GEMM =================
__global__ __launch_bounds__(256, 8) void fused_l1(
    const float* __restrict__ x8, const int* __restrict__ rowstart,
    const int* __restrict__ eidx,
    const float* __restrict__ W1, const float* __restrict__ B1,
    const unsigned short* __restrict__ W2hi, const unsigned short* __restrict__ W2lo,
    const float* __restrict__ B2, _Float16* __restrict__ Out, int M)
{
  __shared__ _Float16 ybuf[64 * 128];  // 16 KB
  __shared__ float z1s[64][8];         // 2 KB
  int tid = threadIdx.x;
  int rbase = blockIdx.x * 64;

  // ---- phase 0: gather x8 rows, 4 lanes/node, unrolled pairs ----
  {
    int node = tid >> 2, sub = tid & 3;
    int c = (sub & 1) * 4, par = sub >> 1;
    int v = rbase + node;
    int vc = (v < M) ? v : (M - 1);
    const float* Xc = x8 + c;
    float4 a = {0.f, 0.f, 0.f, 0.f};
    float4 a1 = {0.f, 0.f, 0.f, 0.f};
    if (!par) a = *(const float4*)&Xc[(long)vc * 8];
    int e0 = rowstart[vc], e1 = rowstart[vc + 1];
    int e = e0 + par;
    for (; e + 2 < e1; e += 4) {
      int s0 = eidx[e], s1 = eidx[e + 2];
      float4 h0 = *(const float4*)&Xc[(long)s0 * 8];
      float4 h1 = *(const float4*)&Xc[(long)s1 * 8];
      a.x += h0.x; a.y += h0.y; a.z += h0.z; a.w += h0.w;
      a1.x += h1.x; a1.y += h1.y; a1.z += h1.z; a1.w += h1.w;
    }
    for (; e < e1; e += 2) {
      int s = eidx[e];
      float4 h = *(const float4*)&Xc[(long)s * 8];
      a.x += h.x; a.y += h.y; a.z += h.z; a.w += h.w;
    }
    a.x += a1.x; a.y += a1.y; a.z += a1.z; a.w += a1.w;
    if (par) *(float4*)&z1s[node][c] = a;
    __syncthreads();
    if (!par) {
      float4 b = *(const float4*)&z1s[node][c];
      a.x += b.x; a.y += b.y; a.z += b.z; a.w += b.w;
      *(float4*)&z1s[node][c] = a;
    }
  }
  __syncthreads();

  // ---- phase A: K=7 GEMM into fp16 LDS ----
  {
    int c = tid & 127;
    int cidx = c >> 3, celt = c & 7;
    int rh0 = (tid >> 7) * 32;
    float w1r[7];
#pragma unroll
    for (int k = 0; k < 7; ++k) w1r[k] = W1[k * 128 + c];
    float b1 = B1[c];
#pragma unroll 4
    for (int rr = 0; rr < 32; ++rr) {
      int r = rh0 + rr;
      const float* zp = z1s[r];
      float a = b1;
#pragma unroll
      for (int k = 0; k < 7; ++k) a += zp[k] * w1r[k];
      ybuf[r * 128 + ((cidx + r) & 15) * 8 + celt] = (_Float16)fmaxf(a, 0.f);
    }
  }
  __syncthreads();

  int lane = tid & 63;
  int wv = tid >> 6;
  int m16 = lane & 15;
  int quad = lane >> 4;
  int rw = wv * 16;

  f32x4 acc[8];
#pragma unroll
  for (int t = 0; t < 8; ++t) acc[t] = (f32x4){0.f, 0.f, 0.f, 0.f};
  mfma_pass(ybuf, W2hi, W2lo, rw, m16, quad, lane, acc);

  float bias[8];
#pragma unroll
  for (int t = 0; t < 8; ++t) bias[t] = B2[t * 16 + m16];

#pragma unroll
  for (int i = 0; i < 4; ++i) {
    int r = rbase + rw + quad * 4 + i;
    if (r < M) {
#pragma unroll
      for (int t = 0; t < 8; ++t) {
        float o = fmaxf(acc[t][i] + bias[t], 0.f);
        Out[(long)r * 128 + t * 16 + m16] = (_Float16)o;
      }
    }
  }
}

// ================= pooling (fp16 H), run-length compressed =================
template <bool DO_CNT>
__global__ __launch_bounds__(256) void pool128(
    const _Float16* __restrict__ H, const int* __restrict__ batch,
    float* __restrict__ P, float* __restrict__ cnt, int Nn, int colOff)
{
  long t = (long)blockIdx.x * 256 + threadIdx.x;
  int cg = (int)(t & 31);
  int chunk = (int)(t >> 5);
  int i0 = chunk * 16;
  if (i0 >= Nn) return;
  int c = cg * 4;
  float4 acc = {0.f, 0.f, 0.f, 0.f};
  int curb = -1;
  float runc = 0.f;
  for (int ii = 0; ii < 16; ++ii) {
    int i = i0 + ii;
    if (i >= Nn) break;
    int b = batch[i];
    if (b != curb) {
      if (curb >= 0) {
        float* p = &P[(long)curb * 384 + colOff + c];
        atomicAdd(p + 0, acc.x); atomicAdd(p + 1, acc.y);
        atomicAdd(p + 2, acc.z); atomicAdd(p + 3, acc.w);
        if (DO_CNT && cg == 0) atomicAdd(&cnt[curb], runc);
      }
      acc.x = acc.y = acc.z = acc.w = 0.f;
      runc = 0.f;
      curb = b;
    }
    h16x4 v = *(const h16x4*)&H[(long)i * 128 + c];
    acc.x += (float)v[0]; acc.y += (float)v[1]; acc.z += (float)v[2]; acc.w += (float)v[3];
    runc += 1.f;
  }
  if (curb >= 0) {
    float* p = &P[(long)curb * 384 + colOff + c];
    atomicAdd(p + 0, acc.x); atomicAdd(p + 1, acc.y);
    atomicAdd(p + 2, acc.z); atomicAdd(p + 3, acc.w);
    if (DO_CNT && cg == 0) atomicAdd(&cnt[curb], runc);
  }
}

// ================= head part 1: G = P@jkw + cnt*jkb; zc = G@c1w + c1b; BN stat atomics =================
// grid = NGRAPH/16 blocks; block handles 16 graph rows; G tile in LDS
__global__ __launch_bounds__(256) void head1(
    const float* __restrict__ P, const float* __restrict__ cnt,
    const float* __restrict__ jkw, const float* __restrict__ jkb,
    const float* __restrict__ c1w, const float* __restrict__ c1b,
    float* __restrict__ zc, float* __restrict__ bnsum, float* __restrict__ bnsumsq)
{
  __shared__ float G[16][128];
  int tid = threadIdx.x;
  int c = tid & 127, rh = tid >> 7;     // rh 0..1, 8 rows each
  int rbase = blockIdx.x * 16;

  float jb = jkb[c];
#pragma unroll
  for (int rr = 0; rr < 8; ++rr) {
    int rl = rh * 8 + rr;
    int r = rbase + rl;
    const float* Pr = &P[(long)r * 384];
    float acc = cnt[r] * jb;
#pragma unroll 4
    for (int k = 0; k < 384; ++k) acc += Pr[k] * jkw[k * 128 + c];
    G[rl][c] = acc;
  }
  __syncthreads();

  float cb = c1b[c];
  float s = 0.f, s2 = 0.f;
#pragma unroll
  for (int rr = 0; rr < 8; ++rr) {
    int rl = rh * 8 + rr;
    float acc = cb;
#pragma unroll 4
    for (int k = 0; k < 128; ++k) acc += G[rl][k] * c1w[k * 128 + c];
    zc[(long)(rbase + rl) * 128 + c] = acc;
    s += acc; s2 += acc * acc;
  }
  atomicAdd(&bnsum[c], s);
  atomicAdd(&bnsumsq[c], s2);
}

// ================= head part 2: BN scale/shift from sums + relu + final [128x2] matmul =================
__global__ __launch_bounds__(256) void bn_final(
    const float* __restrict__ ZC, const float* __restrict__ bnsum, const float* __restrict__ bnsumsq,
    const float* __restrict__ gma, const float* __restrict__ bta,
    const float* __restrict__ W2, const float* __restrict__ B2, float* __restrict__ out)
{
  __shared__ float scl[128], shf[128];
  int tid = threadIdx.x;
  if (tid < 128) {
    float mu = bnsum[tid] * (1.f / NGRAPH);
    float var = bnsumsq[tid] * (1.f / NGRAPH) - mu * mu;
    float rs = rsqrtf(var + 1e-5f);
    float sc = gma[tid] * rs;
    scl[tid] = sc;
    shf[tid] = bta[tid] - mu * sc;
  }
  __syncthreads();
  int g = blockIdx.x * 256 + tid;
  if (g >= NGRAPH) return;
  float a0 = B2[0], a1 = B2[1];
#pragma unroll 4
  for (int h = 0; h < 128; ++h) {
    float zn = ZC[(long)g * 128 + h] * scl[h] + shf[h];
    zn = fmaxf(zn, 0.f);
    a0 += zn * W2[2 * h];
    a1 += zn * W2[2 * h + 1];
  }
  out[2 * g] = a0;
  out[2 * g + 1] = a1;
}

extern "C" void kernel_launch(void* const* d_in, const int* in_sizes, int n_in,
                              void* d_out, int out_size, void* d_ws, size_t ws_size,
                              hipStream_t stream)
{
  const float* x    = (const float*)d_in[0];
  const int*   ei   = (const int*)d_in[1];
  const int*   batch = (const int*)d_in[3];
  const float* g1w1 = (const float*)d_in[4];  const float* g1b1 = (const float*)d_in[5];
  const float* g1w2 = (const float*)d_in[6];  const float* g1b2 = (const float*)d_in[7];
  const float* g2w1 = (const float*)d_in[8];  const float* g2b1 = (const float*)d_in[9];
  const float* g2w2 = (const float*)d_in[10]; const float* g2b2 = (const float*)d_in[11];
  const float* g3w1 = (const float*)d_in[12]; const float* g3b1 = (const float*)d_in[13];
  const float* g3w2 = (const float*)d_in[14]; const float* g3b2 = (const float*)d_in[15];
  const float* jkw  = (const float*)d_in[16]; const float* jkb  = (const float*)d_in[17];
  const float* c1w  = (const float*)d_in[18]; const float* c1b  = (const float*)d_in[19];
  const float* bng  = (const float*)d_in[20]; const float* bnb  = (const float*)d_in[21];
  const float* c2w  = (const float*)d_in[22]; const float* c2b  = (const float*)d_in[23];

  const int N = in_sizes[3];
  const int E = in_sizes[1] / 2;
  const int* src = ei;
  const int* dst = ei + E;

  char* w = (char*)d_ws;
  auto alloc = [&](size_t bytes) {
    char* p = w;
    w += (bytes + 255) & ~(size_t)255;
    return p;
  };
  _Float16* hA = (_Float16*)alloc((size_t)N * 128 * 2);
  _Float16* hB = (_Float16*)alloc((size_t)N * 128 * 2);
  float* x8   = (float*)alloc((size_t)N * 8 * 4);
  // P, cnt, bnsum, bnsumsq contiguous -> one memset
  float* P       = (float*)alloc((size_t)NGRAPH * 384 * 4);
  float* cnt     = (float*)alloc((size_t)NGRAPH * 4);
  float* bnsum   = (float*)alloc(128 * 4);
  float* bnsumsq = (float*)alloc(128 * 4);
  float* zc   = (float*)alloc((size_t)NGRAPH * 128 * 4);
  int* deg      = (int*)alloc((size_t)N * 4);              // deg and cursor contiguous
  int* cursor   = (int*)alloc((size_t)N * 4);
  int* rowstart = (int*)alloc((size_t)(N + 1) * 4);
  int* bsum     = (int*)alloc((size_t)1024 * 4);
  int* eidx     = (int*)alloc((size_t)E * 4);
  unsigned short* wtbuf = (unsigned short*)alloc((size_t)5 * 2 * 16384 * 2);

  unsigned short* WThi[5];
  unsigned short* WTlo[5];
  for (int m = 0; m < 5; ++m) {
    WThi[m] = wtbuf + (size_t)m * 2 * 16384;
    WTlo[m] = WThi[m] + 16384;
  }

  const int nb = (N + 255) / 256;
  const int eb = (E + 255) / 256;
  const size_t npad = ((size_t)N * 4 + 255) & ~(size_t)255;

  // ---- memset deg+cursor (contiguous) ----
  hipMemsetAsync(deg, 0, npad + (size_t)N * 4, stream);
  // ---- memset P+cnt+bnsum+bnsumsq (contiguous; sizes are 256-multiples) ----
  hipMemsetAsync(P, 0, (size_t)NGRAPH * 384 * 4 + (size_t)NGRAPH * 4 + 256 + 256, stream);

  // ---- merged hist + weight prep + x pad ----
  {
    WPs p;
    p.w[0] = g1w2; p.w[1] = g2w1; p.w[2] = g2w2; p.w[3] = g3w1; p.w[4] = g3w2;
    for (int m = 0; m < 5; ++m) { p.hi[m] = WThi[m]; p.lo[m] = WTlo[m]; }
    int total = E + 5 * 16384 + N * 8;
    prep_hist<<<(total + 255) / 256, 256, 0, stream>>>(p, x, x8, N, dst, deg, E);
  }

  // ---- scan + fill ----
  scan1<<<nb, 256, 0, stream>>>(deg, rowstart, bsum, N);
  scan2<<<1, 1024, 0, stream>>>(bsum, nb, rowstart, N, E);
  scan3<<<nb, 256, 0, stream>>>(rowstart, bsum, N);
  fill_eidx<<<eb, 256, 0, stream>>>(src, dst, rowstart, cursor, eidx, E);

  const int fBlocks = (N + 63) / 64;
  const int poolBlocks = (((N + 15) / 16) * 32 + 255) / 256;

  // ---- layer 1 (gather + MLP fused) ----
  fused_l1<<<fBlocks, 256, 0, stream>>>(x8, rowstart, eidx, g1w1, g1b1,
      WThi[0], WTlo[0], g1b2, hA, N);
  pool128<true><<<poolBlocks, 256, 0, stream>>>(hA, batch, P, cnt, N, 0);

  // ---- layer 2 ----
  fused_gin<<<fBlocks, 256, 0, stream>>>(hA, rowstart, eidx,
      WThi[1], WTlo[1], g2b1, WThi[2], WTlo[2], g2b2, hB, N);
  pool128<false><<<poolBlocks, 256, 0, stream>>>(hB, batch, P, cnt, N, 128);

  // ---- layer 3 ----
  fused_gin<<<fBlocks, 256, 0, stream>>>(hB, rowstart, eidx,
      WThi[3], WTlo[3], g3b1, WThi[4], WTlo[4], g3b2, hA, N);
  pool128<false><<<poolBlocks, 256, 0, stream>>>(hA, batch, P, cnt, N, 256);

  // ---- head (2 kernels) ----
  head1<<<NGRAPH / 16, 256, 0, stream>>>(P, cnt, jkw, jkb, c1w, c1b, zc, bnsum, bnsumsq);
  bn_final<<<(NGRAPH + 255) / 256, 256, 0, stream>>>(zc, bnsum, bnsumsq, bng, bnb, c2w, c2b, (float*)d_out);
}

// Round 12
// 460.743 us; speedup vs baseline: 1.2138x; 1.2138x over previous
//
#include <hip/hip_runtime.h>

#define NGRAPH 2048

typedef __attribute__((ext_vector_type(8))) short bf16x8;
typedef __attribute__((ext_vector_type(4))) float f32x4;
typedef __attribute__((ext_vector_type(8))) _Float16 h16x8;
typedef __attribute__((ext_vector_type(4))) _Float16 h16x4;

__device__ inline unsigned short bf16_rne(float f) {
  union { float f; unsigned u; } c; c.f = f;
  unsigned u = c.u + 0x7fffu + ((c.u >> 16) & 1u);
  return (unsigned short)(u >> 16);
}
__device__ inline float bf16_to_f32(unsigned short h) {
  union { float f; unsigned u; } c; c.u = ((unsigned)h) << 16;
  return c.f;
}

// ================= CSR build =================
__global__ __launch_bounds__(256) void scan1(
    const int* __restrict__ deg, int* __restrict__ rowstart, int* __restrict__ bsum, int N)
{
  __shared__ int tmp[256];
  int i = blockIdx.x * 256 + threadIdx.x;
  int v = (i < N) ? deg[i] : 0;
  tmp[threadIdx.x] = v;
  __syncthreads();
#pragma unroll
  for (int off = 1; off < 256; off <<= 1) {
    int t = (threadIdx.x >= (unsigned)off) ? tmp[threadIdx.x - off] : 0;
    __syncthreads();
    tmp[threadIdx.x] += t;
    __syncthreads();
  }
  if (i < N) rowstart[i] = tmp[threadIdx.x] - v;
  if (threadIdx.x == 255) bsum[blockIdx.x] = tmp[255];
}

__global__ __launch_bounds__(1024) void scan2(
    int* __restrict__ bsum, int nb, int* __restrict__ rowstart, int N, int E)
{
  __shared__ int tmp[1024];
  int i = threadIdx.x;
  int v = (i < nb) ? bsum[i] : 0;
  tmp[i] = v;
  __syncthreads();
#pragma unroll
  for (int off = 1; off < 1024; off <<= 1) {
    int t = (i >= off) ? tmp[i - off] : 0;
    __syncthreads();
    tmp[i] += t;
    __syncthreads();
  }
  if (i < nb) bsum[i] = tmp[i] - v;
  if (i == 0) rowstart[N] = E;
}

__global__ __launch_bounds__(256) void scan3(
    int* __restrict__ rowstart, const int* __restrict__ bsum, int N)
{
  int i = blockIdx.x * 256 + threadIdx.x;
  if (i < N) rowstart[i] += bsum[blockIdx.x];
}

__global__ __launch_bounds__(256) void fill_eidx(
    const int* __restrict__ src, const int* __restrict__ dst,
    const int* __restrict__ rowstart, int* __restrict__ cursor,
    int* __restrict__ eidx, int E)
{
  int e = blockIdx.x * 256 + threadIdx.x;
  if (e >= E) return;
  int d = dst[e];
  int pos = rowstart[d] + atomicAdd(&cursor[d], 1);
  eidx[pos] = src[e];
}

// ================= merged: degree histogram + 5x weight frag-repack + x pad =================
struct WPs {
  const float* w[5];
  unsigned short* hi[5];
  unsigned short* lo[5];
};
__global__ __launch_bounds__(256) void prep_hist(
    WPs p, const float* __restrict__ x, float* __restrict__ x8, int N,
    const int* __restrict__ dst, int* __restrict__ deg, int E)
{
  int g = blockIdx.x * 256 + threadIdx.x;
  if (g < E) {
    atomicAdd(&deg[dst[g]], 1);
    return;
  }
  int q = g - E;
  if (q < 5 * 16384) {
    int m = q >> 14;
    int j = q & 16383;
    int c = j >> 3, e = j & 7;
    int t = c >> 8, kc = (c >> 6) & 3, lane = c & 63;
    int n = t * 16 + (lane & 15);
    int k = kc * 32 + (lane >> 4) * 8 + e;
    float w = p.w[m][k * 128 + n];
    unsigned short h = bf16_rne(w);
    float r = w - bf16_to_f32(h);
    p.hi[m][j] = h;
    p.lo[m][j] = bf16_rne(r);
  } else {
    int i = q - 5 * 16384;
    if (i < N * 8) {
      int v = i >> 3, j = i & 7;
      x8[i] = (j < 7) ? x[v * 7 + j] : 0.f;
    }
  }
}

// ---- split-precision GEMM pass over a 64x128 fp16 LDS tile (chunk-rot swizzle) ----
__device__ inline void mfma_pass(
    const _Float16* __restrict__ zbuf,
    const unsigned short* __restrict__ Whi, const unsigned short* __restrict__ Wlo,
    int rw, int m16, int quad, int lane, f32x4 acc[8])
{
  int r = rw + m16;
  const _Float16* zrow = &zbuf[r * 128];
#pragma unroll
  for (int kc = 0; kc < 4; ++kc) {
    int cidx = kc * 4 + quad;
    h16x8 zh = *(const h16x8*)&zrow[((cidx + r) & 15) * 8];
    bf16x8 ah, al;
#pragma unroll
    for (int j = 0; j < 8; ++j) {
      float f = (float)zh[j];
      unsigned short h = bf16_rne(f);
      ah[j] = (short)h;
      al[j] = (short)bf16_rne(f - bf16_to_f32(h));
    }
#pragma unroll
    for (int t = 0; t < 8; ++t) {
      long cb = ((t * 4 + kc) * 64 + lane) * 8;
      bf16x8 bh = *(const bf16x8*)&Whi[cb];
      bf16x8 bl = *(const bf16x8*)&Wlo[cb];
      acc[t] = __builtin_amdgcn_mfma_f32_16x16x32_bf16(ah, bh, acc[t], 0, 0, 0);
      acc[t] = __builtin_amdgcn_mfma_f32_16x16x32_bf16(ah, bl, acc[t], 0, 0, 0);
      acc[t] = __builtin_amdgcn_mfma_f32_16x16x32_bf16(al, bh, acc[t], 0, 0, 0);
    }
  }
}

// ================= fused GIN layer (layers 2,3): gather + MLP1 + MLP2 =================
__global__ __launch_bounds__(256, 8) void fused_gin(
    const _Float16* __restrict__ H, const int* __restrict__ rowstart,
    const int* __restrict__ eidx,
    const unsigned short* __restrict__ W1hi, const unsigned short* __restrict__ W1lo,
    const float* __restrict__ B1,
    const unsigned short* __restrict__ W2hi, const unsigned short* __restrict__ W2lo,
    const float* __restrict__ B2,
    _Float16* __restrict__ Out, int M)
{
  __shared__ _Float16 zbuf[64 * 128];   // 16 KB
  int tid = threadIdx.x;
  int rbase = blockIdx.x * 64;

  // ---- phase 1: gather 64 rows; 16 lanes x 16B per row, 4-edge unroll ----
  {
    int sub = tid & 15;
    int ng = tid >> 4;
    const _Float16* Hc = H + sub * 8;
#pragma unroll
    for (int it = 0; it < 4; ++it) {
      int r = it * 16 + ng;
      int v = rbase + r;
      int vc = (v < M) ? v : (M - 1);
      h16x8 sv = *(const h16x8*)&Hc[(long)vc * 128];
      float a0[8], a1[8];
#pragma unroll
      for (int j = 0; j < 8; ++j) { a0[j] = (float)sv[j]; a1[j] = 0.f; }
      int e0 = rowstart[vc], e1 = rowstart[vc + 1];
      int e = e0;
      for (; e + 4 <= e1; e += 4) {
        int s0 = eidx[e], s1 = eidx[e + 1], s2 = eidx[e + 2], s3 = eidx[e + 3];
        h16x8 h0 = *(const h16x8*)&Hc[(long)s0 * 128];
        h16x8 h1 = *(const h16x8*)&Hc[(long)s1 * 128];
        h16x8 h2 = *(const h16x8*)&Hc[(long)s2 * 128];
        h16x8 h3 = *(const h16x8*)&Hc[(long)s3 * 128];
#pragma unroll
        for (int j = 0; j < 8; ++j) {
          a0[j] += (float)h0[j] + (float)h2[j];
          a1[j] += (float)h1[j] + (float)h3[j];
        }
      }
      for (; e < e1; ++e) {
        int s = eidx[e];
        h16x8 h = *(const h16x8*)&Hc[(long)s * 128];
#pragma unroll
        for (int j = 0; j < 8; ++j) a1[j] += (float)h[j];
      }
      h16x8 zo;
#pragma unroll
      for (int j = 0; j < 8; ++j) zo[j] = (_Float16)(a0[j] + a1[j]);
      *(h16x8*)&zbuf[r * 128 + ((sub + r) & 15) * 8] = zo;
    }
  }
  __syncthreads();

  int lane = tid & 63;
  int wv = tid >> 6;
  int m16 = lane & 15;
  int quad = lane >> 4;
  int rw = wv * 16;

  // ---- phase 2: y = relu(z @ W1 + b1) ----
  f32x4 acc[8];
#pragma unroll
  for (int t = 0; t < 8; ++t) acc[t] = (f32x4){0.f, 0.f, 0.f, 0.f};
  mfma_pass(zbuf, W1hi, W1lo, rw, m16, quad, lane, acc);

  float bias[8];
#pragma unroll
  for (int t = 0; t < 8; ++t) bias[t] = B1[t * 16 + m16];

  __syncthreads();
#pragma unroll
  for (int i = 0; i < 4; ++i) {
    int r = rw + quad * 4 + i;
#pragma unroll
    for (int t = 0; t < 8; ++t) {
      int col = t * 16 + m16;
      int cidx = col >> 3;
      zbuf[r * 128 + ((cidx + r) & 15) * 8 + (col & 7)] =
          (_Float16)fmaxf(acc[t][i] + bias[t], 0.f);
    }
  }
  __syncthreads();

  // ---- phase 3: Hout = relu(y @ W2 + b2), direct scattered fp16 stores ----
#pragma unroll
  for (int t = 0; t < 8; ++t) acc[t] = (f32x4){0.f, 0.f, 0.f, 0.f};
  mfma_pass(zbuf, W2hi, W2lo, rw, m16, quad, lane, acc);

#pragma unroll
  for (int t = 0; t < 8; ++t) bias[t] = B2[t * 16 + m16];

#pragma unroll
  for (int i = 0; i < 4; ++i) {
    int r = rbase + rw + quad * 4 + i;
    if (r < M) {
#pragma unroll
      for (int t = 0; t < 8; ++t) {
        float o = fmaxf(acc[t][i] + bias[t], 0.f);
        Out[(long)r * 128 + t * 16 + m16] = (_Float16)o;
      }
    }
  }
}

// ================= fused layer 1: gather(x8) + K=7 GEMM + MFMA GEMM =================
__global__ __launch_bounds__(256, 8) void fused_l1(
    const float* __restrict__ x8, const int* __restrict__ rowstart,
    const int* __restrict__ eidx,
    const float* __restrict__ W1, const float* __restrict__ B1,
    const unsigned short* __restrict__ W2hi, const unsigned short* __restrict__ W2lo,
    const float* __restrict__ B2, _Float16* __restrict__ Out, int M)
{
  __shared__ _Float16 ybuf[64 * 128];  // 16 KB
  __shared__ float z1s[64][8];         // 2 KB
  int tid = threadIdx.x;
  int rbase = blockIdx.x * 64;

  // ---- phase 0: gather x8 rows, 4 lanes/node, unrolled pairs ----
  {
    int node = tid >> 2, sub = tid & 3;
    int c = (sub & 1) * 4, par = sub >> 1;
    int v = rbase + node;
    int vc = (v < M) ? v : (M - 1);
    const float* Xc = x8 + c;
    float4 a = {0.f, 0.f, 0.f, 0.f};
    float4 a1 = {0.f, 0.f, 0.f, 0.f};
    if (!par) a = *(const float4*)&Xc[(long)vc * 8];
    int e0 = rowstart[vc], e1 = rowstart[vc + 1];
    int e = e0 + par;
    for (; e + 2 < e1; e += 4) {
      int s0 = eidx[e], s1 = eidx[e + 2];
      float4 h0 = *(const float4*)&Xc[(long)s0 * 8];
      float4 h1 = *(const float4*)&Xc[(long)s1 * 8];
      a.x += h0.x; a.y += h0.y; a.z += h0.z; a.w += h0.w;
      a1.x += h1.x; a1.y += h1.y; a1.z += h1.z; a1.w += h1.w;
    }
    for (; e < e1; e += 2) {
      int s = eidx[e];
      float4 h = *(const float4*)&Xc[(long)s * 8];
      a.x += h.x; a.y += h.y; a.z += h.z; a.w += h.w;
    }
    a.x += a1.x; a.y += a1.y; a.z += a1.z; a.w += a1.w;
    if (par) *(float4*)&z1s[node][c] = a;
    __syncthreads();
    if (!par) {
      float4 b = *(const float4*)&z1s[node][c];
      a.x += b.x; a.y += b.y; a.z += b.z; a.w += b.w;
      *(float4*)&z1s[node][c] = a;
    }
  }
  __syncthreads();

  // ---- phase A: K=7 GEMM into fp16 LDS ----
  {
    int c = tid & 127;
    int cidx = c >> 3, celt = c & 7;
    int rh0 = (tid >> 7) * 32;
    float w1r[7];
#pragma unroll
    for (int k = 0; k < 7; ++k) w1r[k] = W1[k * 128 + c];
    float b1 = B1[c];
#pragma unroll 4
    for (int rr = 0; rr < 32; ++rr) {
      int r = rh0 + rr;
      const float* zp = z1s[r];
      float a = b1;
#pragma unroll
      for (int k = 0; k < 7; ++k) a += zp[k] * w1r[k];
      ybuf[r * 128 + ((cidx + r) & 15) * 8 + celt] = (_Float16)fmaxf(a, 0.f);
    }
  }
  __syncthreads();

  int lane = tid & 63;
  int wv = tid >> 6;
  int m16 = lane & 15;
  int quad = lane >> 4;
  int rw = wv * 16;

  f32x4 acc[8];
#pragma unroll
  for (int t = 0; t < 8; ++t) acc[t] = (f32x4){0.f, 0.f, 0.f, 0.f};
  mfma_pass(ybuf, W2hi, W2lo, rw, m16, quad, lane, acc);

  float bias[8];
#pragma unroll
  for (int t = 0; t < 8; ++t) bias[t] = B2[t * 16 + m16];

#pragma unroll
  for (int i = 0; i < 4; ++i) {
    int r = rbase + rw + quad * 4 + i;
    if (r < M) {
#pragma unroll
      for (int t = 0; t < 8; ++t) {
        float o = fmaxf(acc[t][i] + bias[t], 0.f);
        Out[(long)r * 128 + t * 16 + m16] = (_Float16)o;
      }
    }
  }
}

// ================= pooling (fp16 H), run-length compressed =================
template <bool DO_CNT>
__global__ __launch_bounds__(256) void pool128(
    const _Float16* __restrict__ H, const int* __restrict__ batch,
    float* __restrict__ P, float* __restrict__ cnt, int Nn, int colOff)
{
  long t = (long)blockIdx.x * 256 + threadIdx.x;
  int cg = (int)(t & 31);
  int chunk = (int)(t >> 5);
  int i0 = chunk * 16;
  if (i0 >= Nn) return;
  int c = cg * 4;
  float4 acc = {0.f, 0.f, 0.f, 0.f};
  int curb = -1;
  float runc = 0.f;
  for (int ii = 0; ii < 16; ++ii) {
    int i = i0 + ii;
    if (i >= Nn) break;
    int b = batch[i];
    if (b != curb) {
      if (curb >= 0) {
        float* p = &P[(long)curb * 384 + colOff + c];
        atomicAdd(p + 0, acc.x); atomicAdd(p + 1, acc.y);
        atomicAdd(p + 2, acc.z); atomicAdd(p + 3, acc.w);
        if (DO_CNT && cg == 0) atomicAdd(&cnt[curb], runc);
      }
      acc.x = acc.y = acc.z = acc.w = 0.f;
      runc = 0.f;
      curb = b;
    }
    h16x4 v = *(const h16x4*)&H[(long)i * 128 + c];
    acc.x += (float)v[0]; acc.y += (float)v[1]; acc.z += (float)v[2]; acc.w += (float)v[3];
    runc += 1.f;
  }
  if (curb >= 0) {
    float* p = &P[(long)curb * 384 + colOff + c];
    atomicAdd(p + 0, acc.x); atomicAdd(p + 1, acc.y);
    atomicAdd(p + 2, acc.z); atomicAdd(p + 3, acc.w);
    if (DO_CNT && cg == 0) atomicAdd(&cnt[curb], runc);
  }
}

// ================= JK: G = P(2048x384) @ W(384x128) + cnt*B  (1024 blocks) =================
__global__ __launch_bounds__(256) void jk_gemm(
    const float* __restrict__ P, const float* __restrict__ cnt,
    const float* __restrict__ W, const float* __restrict__ B,
    float* __restrict__ G)
{
  __shared__ float pl[768];
  int tid = threadIdx.x, blk = blockIdx.x;
  for (int o = tid; o < 768; o += 256) pl[o] = P[(long)blk * 768 + o];
  __syncthreads();
  int rr = tid >> 7;
  int col = tid & 127;
  int row = blk * 2 + rr;
  float acc = cnt[row] * B[col];
#pragma unroll 8
  for (int k = 0; k < 384; ++k)
    acc += pl[rr * 384 + k] * W[k * 128 + col];
  G[(long)row * 128 + col] = acc;
}

// ================= classifier GEMM + BN stat atomics: zc = G@c1w + c1b =================
__global__ __launch_bounds__(256) void gemm_bn(
    const float* __restrict__ Z,
    const float* __restrict__ W, const float* __restrict__ B,
    float* __restrict__ Out, float* __restrict__ bnsum, float* __restrict__ bnsumsq, int M)
{
  __shared__ float wlds[128 * 128];
  int tid = threadIdx.x;
  {
    const float4* Ws = (const float4*)W;
    float4* Wd = (float4*)wlds;
#pragma unroll
    for (int i = 0; i < 16; ++i) Wd[i * 256 + tid] = Ws[i * 256 + tid];
  }
  __syncthreads();

  int rg = tid >> 5;
  int c0 = (tid & 31) * 4;
  int rbase = blockIdx.x * 64 + rg * 8;

  float acc[8][4];
#pragma unroll
  for (int i = 0; i < 8; ++i)
#pragma unroll
    for (int j = 0; j < 4; ++j) acc[i][j] = 0.f;

#pragma unroll 2
  for (int kc = 0; kc < 128; kc += 4) {
    float zv[8][4];
#pragma unroll
    for (int i = 0; i < 8; ++i) {
      float4 z = *(const float4*)&Z[(long)(rbase + i) * 128 + kc];
      zv[i][0] = z.x; zv[i][1] = z.y; zv[i][2] = z.z; zv[i][3] = z.w;
    }
#pragma unroll
    for (int kk = 0; kk < 4; ++kk) {
      float4 w = *(const float4*)&wlds[(kc + kk) * 128 + c0];
#pragma unroll
      for (int i = 0; i < 8; ++i) {
        float z = zv[i][kk];
        acc[i][0] += z * w.x; acc[i][1] += z * w.y;
        acc[i][2] += z * w.z; acc[i][3] += z * w.w;
      }
    }
  }

  float4 b = *(const float4*)&B[c0];
  float s[4] = {0.f, 0.f, 0.f, 0.f};
  float s2[4] = {0.f, 0.f, 0.f, 0.f};
#pragma unroll
  for (int i = 0; i < 8; ++i) {
    float4 o;
    o.x = acc[i][0] + b.x; o.y = acc[i][1] + b.y;
    o.z = acc[i][2] + b.z; o.w = acc[i][3] + b.w;
    *(float4*)&Out[(long)(rbase + i) * 128 + c0] = o;
    s[0] += o.x; s[1] += o.y; s[2] += o.z; s[3] += o.w;
    s2[0] += o.x * o.x; s2[1] += o.y * o.y; s2[2] += o.z * o.z; s2[3] += o.w * o.w;
  }
#pragma unroll
  for (int j = 0; j < 4; ++j) {
    atomicAdd(&bnsum[c0 + j], s[j]);
    atomicAdd(&bnsumsq[c0 + j], s2[j]);
  }
}

// ================= BN scale/shift from sums + relu + final [128x2] matmul =================
__global__ __launch_bounds__(256) void bn_final(
    const float* __restrict__ ZC, const float* __restrict__ bnsum, const float* __restrict__ bnsumsq,
    const float* __restrict__ gma, const float* __restrict__ bta,
    const float* __restrict__ W2, const float* __restrict__ B2, float* __restrict__ out)
{
  __shared__ float scl[128], shf[128];
  int tid = threadIdx.x;
  if (tid < 128) {
    float mu = bnsum[tid] * (1.f / NGRAPH);
    float var = bnsumsq[tid] * (1.f / NGRAPH) - mu * mu;
    float rs = rsqrtf(var + 1e-5f);
    float sc = gma[tid] * rs;
    scl[tid] = sc;
    shf[tid] = bta[tid] - mu * sc;
  }
  __syncthreads();
  int g = blockIdx.x * 256 + tid;
  if (g >= NGRAPH) return;
  float a0 = B2[0], a1 = B2[1];
#pragma unroll 4
  for (int h = 0; h < 128; ++h) {
    float zn = ZC[(long)g * 128 + h] * scl[h] + shf[h];
    zn = fmaxf(zn, 0.f);
    a0 += zn * W2[2 * h];
    a1 += zn * W2[2 * h + 1];
  }
  out[2 * g] = a0;
  out[2 * g + 1] = a1;
}

extern "C" void kernel_launch(void* const* d_in, const int* in_sizes, int n_in,
                              void* d_out, int out_size, void* d_ws, size_t ws_size,
                              hipStream_t stream)
{
  const float* x    = (const float*)d_in[0];
  const int*   ei   = (const int*)d_in[1];
  const int*   batch = (const int*)d_in[3];
  const float* g1w1 = (const float*)d_in[4];  const float* g1b1 = (const float*)d_in[5];
  const float* g1w2 = (const float*)d_in[6];  const float* g1b2 = (const float*)d_in[7];
  const float* g2w1 = (const float*)d_in[8];  const float* g2b1 = (const float*)d_in[9];
  const float* g2w2 = (const float*)d_in[10]; const float* g2b2 = (const float*)d_in[11];
  const float* g3w1 = (const float*)d_in[12]; const float* g3b1 = (const float*)d_in[13];
  const float* g3w2 = (const float*)d_in[14]; const float* g3b2 = (const float*)d_in[15];
  const float* jkw  = (const float*)d_in[16]; const float* jkb  = (const float*)d_in[17];
  const float* c1w  = (const float*)d_in[18]; const float* c1b  = (const float*)d_in[19];
  const float* bng  = (const float*)d_in[20]; const float* bnb  = (const float*)d_in[21];
  const float* c2w  = (const float*)d_in[22]; const float* c2b  = (const float*)d_in[23];

  const int N = in_sizes[3];
  const int E = in_sizes[1] / 2;
  const int* src = ei;
  const int* dst = ei + E;

  char* w = (char*)d_ws;
  auto alloc = [&](size_t bytes) {
    char* p = w;
    w += (bytes + 255) & ~(size_t)255;
    return p;
  };
  _Float16* hA = (_Float16*)alloc((size_t)N * 128 * 2);
  _Float16* hB = (_Float16*)alloc((size_t)N * 128 * 2);
  float* x8   = (float*)alloc((size_t)N * 8 * 4);
  // P, cnt, bnsum, bnsumsq contiguous -> one memset
  float* P       = (float*)alloc((size_t)NGRAPH * 384 * 4);
  float* cnt     = (float*)alloc((size_t)NGRAPH * 4);
  float* bnsum   = (float*)alloc(128 * 4);
  float* bnsumsq = (float*)alloc(128 * 4);
  float* gbuf = (float*)alloc((size_t)NGRAPH * 128 * 4);
  float* zc   = (float*)alloc((size_t)NGRAPH * 128 * 4);
  int* deg      = (int*)alloc((size_t)N * 4);              // deg and cursor contiguous
  int* cursor   = (int*)alloc((size_t)N * 4);
  int* rowstart = (int*)alloc((size_t)(N + 1) * 4);
  int* bsum     = (int*)alloc((size_t)1024 * 4);
  int* eidx     = (int*)alloc((size_t)E * 4);
  unsigned short* wtbuf = (unsigned short*)alloc((size_t)5 * 2 * 16384 * 2);

  unsigned short* WThi[5];
  unsigned short* WTlo[5];
  for (int m = 0; m < 5; ++m) {
    WThi[m] = wtbuf + (size_t)m * 2 * 16384;
    WTlo[m] = WThi[m] + 16384;
  }

  const int nb = (N + 255) / 256;
  const int eb = (E + 255) / 256;
  const size_t npad = ((size_t)N * 4 + 255) & ~(size_t)255;

  // ---- memset deg+cursor (contiguous) ----
  hipMemsetAsync(deg, 0, npad + (size_t)N * 4, stream);
  // ---- memset P+cnt+bnsum+bnsumsq (contiguous; sizes are 256-multiples) ----
  hipMemsetAsync(P, 0, (size_t)NGRAPH * 384 * 4 + (size_t)NGRAPH * 4 + 256 + 256, stream);

  // ---- merged hist + weight prep + x pad ----
  {
    WPs p;
    p.w[0] = g1w2; p.w[1] = g2w1; p.w[2] = g2w2; p.w[3] = g3w1; p.w[4] = g3w2;
    for (int m = 0; m < 5; ++m) { p.hi[m] = WThi[m]; p.lo[m] = WTlo[m]; }
    int total = E + 5 * 16384 + N * 8;
    prep_hist<<<(total + 255) / 256, 256, 0, stream>>>(p, x, x8, N, dst, deg, E);
  }

  // ---- scan + fill ----
  scan1<<<nb, 256, 0, stream>>>(deg, rowstart, bsum, N);
  scan2<<<1, 1024, 0, stream>>>(bsum, nb, rowstart, N, E);
  scan3<<<nb, 256, 0, stream>>>(rowstart, bsum, N);
  fill_eidx<<<eb, 256, 0, stream>>>(src, dst, rowstart, cursor, eidx, E);

  const int fBlocks = (N + 63) / 64;
  const int poolBlocks = (((N + 15) / 16) * 32 + 255) / 256;

  // ---- layer 1 (gather + MLP fused) ----
  fused_l1<<<fBlocks, 256, 0, stream>>>(x8, rowstart, eidx, g1w1, g1b1,
      WThi[0], WTlo[0], g1b2, hA, N);
  pool128<true><<<poolBlocks, 256, 0, stream>>>(hA, batch, P, cnt, N, 0);

  // ---- layer 2 ----
  fused_gin<<<fBlocks, 256, 0, stream>>>(hA, rowstart, eidx,
      WThi[1], WTlo[1], g2b1, WThi[2], WTlo[2], g2b2, hB, N);
  pool128<false><<<poolBlocks, 256, 0, stream>>>(hB, batch, P, cnt, N, 128);

  // ---- layer 3 ----
  fused_gin<<<fBlocks, 256, 0, stream>>>(hB, rowstart, eidx,
      WThi[3], WTlo[3], g3b1, WThi[4], WTlo[4], g3b2, hA, N);
  pool128<false><<<poolBlocks, 256, 0, stream>>>(hA, batch, P, cnt, N, 256);

  // ---- head (3 kernels) ----
  jk_gemm<<<NGRAPH / 2, 256, 0, stream>>>(P, cnt, jkw, jkb, gbuf);
  gemm_bn<<<NGRAPH / 64, 256, 0, stream>>>(gbuf, c1w, c1b, zc, bnsum, bnsumsq, NGRAPH);
  bn_final<<<(NGRAPH + 255) / 256, 256, 0, stream>>>(zc, bnsum, bnsumsq, bng, bnb, c2w, c2b, (float*)d_out);
}